// Round 1
// baseline (896.300 us; speedup 1.0000x reference)
//
#include <hip/hip_runtime.h>

#define BB   8
#define MM   2048
#define DD   1024
#define FF   2048
#define NE   32
#define PP   4
#define NPS  128     // NE*PP
#define BMR  16384   // BB*MM

// ---------------------------------------------------------------------------
// K1: logits = x @ phi ; E = exp(logits); Cbuf = row-softmax (combine);
// atomic partial column sums (dispatch denominators).
// Tile 64 rows x 128 slots, K=1024. grid=256, block=256, 4x8 acc/thread.
// Reg-prefetch double-buffered LDS, ONE barrier per K-tile.
// ---------------------------------------------------------------------------
__global__ __launch_bounds__(256) void k1_logits_kernel(
    const float* __restrict__ x, const float* __restrict__ phi,
    float* __restrict__ Ebuf, float* __restrict__ Cbuf, float* __restrict__ colsum)
{
    __shared__ __align__(16) float aA[2][32][68];   // [k][row], pad 68 keeps 16B align
    __shared__ __align__(16) float bB[2][32][128];  // [k][col]
    const int tid  = threadIdx.x;
    const int row0 = blockIdx.x * 64;
    const int bidx = row0 >> 11;           // batch (2048 rows per batch, 64 | 2048)
    const int r0 = (tid >> 4) * 4;         // 0..60 (row group)
    const int c0 = (tid & 15) * 4;         // cols c0..c0+3 and 64+c0..64+c0+3
    const int sa_r = tid >> 2;             // 0..63  a-stage row
    const int sa_k = (tid & 3) * 8;        // 0,8,16,24 a-stage k chunk
    const float* xa = x + (size_t)(row0 + sa_r) * DD + sa_k;

    float4 ar0 = *(const float4*)(xa);
    float4 ar1 = *(const float4*)(xa + 4);
    float4 br[4];
    #pragma unroll
    for (int i = 0; i < 4; ++i) {
        const int idx = tid + 256 * i;
        br[i] = *(const float4*)&phi[(size_t)(idx >> 5) * NPS + (idx & 31) * 4];
    }

    float acc[4][8] = {};
    for (int kt = 0; kt < 32; ++kt) {
        const int buf = kt & 1;
        {
            const float a8[8] = {ar0.x,ar0.y,ar0.z,ar0.w, ar1.x,ar1.y,ar1.z,ar1.w};
            #pragma unroll
            for (int j = 0; j < 8; ++j) aA[buf][sa_k + j][sa_r] = a8[j];
            #pragma unroll
            for (int i = 0; i < 4; ++i) {
                const int idx = tid + 256 * i;
                *(float4*)&bB[buf][idx >> 5][(idx & 31) * 4] = br[i];
            }
        }
        __syncthreads();
        if (kt < 31) {
            const int k0 = (kt + 1) * 32;
            ar0 = *(const float4*)(xa + k0);
            ar1 = *(const float4*)(xa + k0 + 4);
            #pragma unroll
            for (int i = 0; i < 4; ++i) {
                const int idx = tid + 256 * i;
                br[i] = *(const float4*)&phi[(size_t)(k0 + (idx >> 5)) * NPS + (idx & 31) * 4];
            }
        }
        #pragma unroll
        for (int k = 0; k < 32; ++k) {
            const float4 av = *(const float4*)&aA[buf][k][r0];
            const float4 b0 = *(const float4*)&bB[buf][k][c0];
            const float4 b1 = *(const float4*)&bB[buf][k][64 + c0];
            const float arr[4] = {av.x, av.y, av.z, av.w};
            const float brr[8] = {b0.x,b0.y,b0.z,b0.w, b1.x,b1.y,b1.z,b1.w};
            #pragma unroll
            for (int i = 0; i < 4; ++i)
                #pragma unroll
                for (int j = 0; j < 8; ++j)
                    acc[i][j] = fmaf(arr[i], brr[j], acc[i][j]);
        }
        // no trailing barrier: dbuf + the next iteration's barrier guards WAR
    }

    // E = exp(logits). |logits| <~ 5, exp without max-subtraction is safe.
    #pragma unroll
    for (int i = 0; i < 4; ++i)
        #pragma unroll
        for (int j = 0; j < 8; ++j)
            acc[i][j] = __expf(acc[i][j]);

    #pragma unroll
    for (int i = 0; i < 4; ++i) {
        const size_t rb = (size_t)(row0 + r0 + i) * NPS;
        *(float4*)&Ebuf[rb + c0]      = make_float4(acc[i][0], acc[i][1], acc[i][2], acc[i][3]);
        *(float4*)&Ebuf[rb + 64 + c0] = make_float4(acc[i][4], acc[i][5], acc[i][6], acc[i][7]);
    }

    // combine softmax: row sums over all 128 slots (block owns full rows).
    // Overlay on aA[0] (last compute read aA[1]; disjoint, no barrier needed first).
    float* red = (float*)aA;   // [64][16]
    #pragma unroll
    for (int i = 0; i < 4; ++i) {
        float s = 0.f;
        #pragma unroll
        for (int j = 0; j < 8; ++j) s += acc[i][j];
        red[(r0 + i) * 16 + (tid & 15)] = s;
    }
    __syncthreads();
    #pragma unroll
    for (int i = 0; i < 4; ++i) {
        float s = 0.f;
        #pragma unroll
        for (int t = 0; t < 16; ++t) s += red[(r0 + i) * 16 + t];
        const float inv = 1.0f / s;
        const size_t rb = (size_t)(row0 + r0 + i) * NPS;
        *(float4*)&Cbuf[rb + c0]      = make_float4(acc[i][0]*inv, acc[i][1]*inv,
                                                    acc[i][2]*inv, acc[i][3]*inv);
        *(float4*)&Cbuf[rb + 64 + c0] = make_float4(acc[i][4]*inv, acc[i][5]*inv,
                                                    acc[i][6]*inv, acc[i][7]*inv);
    }

    // dispatch denominators: per-column partials over this block's 64 rows.
    float* cred = (float*)bB;  // [128][16], overlay on bB[0]
    const int g = tid >> 4;
    #pragma unroll
    for (int j = 0; j < 8; ++j) {
        const int col = (j < 4) ? (c0 + j) : (64 + c0 + j - 4);
        cred[col * 16 + g] = acc[0][j] + acc[1][j] + acc[2][j] + acc[3][j];
    }
    __syncthreads();
    if (tid < NPS) {
        float s = 0.f;
        #pragma unroll
        for (int t = 0; t < 16; ++t) s += cred[tid * 16 + t];
        atomicAdd(&colsum[bidx * NPS + tid], s);
    }
}

// ---------------------------------------------------------------------------
// K2: xs partials: xsp[ks][b][np][d] = sum_{m in chunk ks} dispatch[b,m,np]*x[b,m,d]
// Tile 64 np x 128 d, split-K x4 (m chunks of 512). grid = 8*2*8*4 = 512.
// 4x8 acc/thread, dbuf + 1 barrier. Normalization (1/colsum) folded in here.
// ---------------------------------------------------------------------------
__global__ __launch_bounds__(256) void k2_xs_kernel(
    const float* __restrict__ Ebuf, const float* __restrict__ x,
    const float* __restrict__ colsum, float* __restrict__ xsp)
{
    __shared__ __align__(16) float aA[2][32][68];   // [k=m][np]
    __shared__ __align__(16) float bB[2][32][128];  // [k=m][d]
    const int tid = threadIdx.x;
    const int bx  = blockIdx.x;
    const int ks  = bx & 3;
    const int dt  = (bx >> 2) & 7;
    const int npt = (bx >> 5) & 1;
    const int b   = bx >> 6;
    const int np0 = npt * 64;
    const int d0  = dt * 128;
    const size_t mb = (size_t)b * MM + ks * 512;
    const int r0 = (tid >> 4) * 4;
    const int c0 = (tid & 15) * 4;

    float4 ea[2], br[4];
    #pragma unroll
    for (int i = 0; i < 2; ++i) {
        const int idx = tid + 256 * i;
        ea[i] = *(const float4*)&Ebuf[(mb + (idx >> 4)) * NPS + np0 + (idx & 15) * 4];
    }
    #pragma unroll
    for (int i = 0; i < 4; ++i) {
        const int idx = tid + 256 * i;
        br[i] = *(const float4*)&x[(mb + (idx >> 5)) * DD + d0 + (idx & 31) * 4];
    }

    float acc[4][8] = {};
    for (int kt = 0; kt < 16; ++kt) {
        const int buf = kt & 1;
        #pragma unroll
        for (int i = 0; i < 2; ++i) {
            const int idx = tid + 256 * i;
            const int am = idx >> 4, ac = (idx & 15) * 4;
            aA[buf][am][ac + 0] = ea[i].x;
            aA[buf][am][ac + 1] = ea[i].y;
            aA[buf][am][ac + 2] = ea[i].z;
            aA[buf][am][ac + 3] = ea[i].w;
        }
        #pragma unroll
        for (int i = 0; i < 4; ++i) {
            const int idx = tid + 256 * i;
            *(float4*)&bB[buf][idx >> 5][(idx & 31) * 4] = br[i];
        }
        __syncthreads();
        if (kt < 15) {
            const int k0 = (kt + 1) * 32;
            #pragma unroll
            for (int i = 0; i < 2; ++i) {
                const int idx = tid + 256 * i;
                ea[i] = *(const float4*)&Ebuf[(mb + k0 + (idx >> 4)) * NPS + np0 + (idx & 15) * 4];
            }
            #pragma unroll
            for (int i = 0; i < 4; ++i) {
                const int idx = tid + 256 * i;
                br[i] = *(const float4*)&x[(mb + k0 + (idx >> 5)) * DD + d0 + (idx & 31) * 4];
            }
        }
        #pragma unroll
        for (int k = 0; k < 32; ++k) {
            const float4 av = *(const float4*)&aA[buf][k][r0];
            const float4 b0 = *(const float4*)&bB[buf][k][c0];
            const float4 b1 = *(const float4*)&bB[buf][k][64 + c0];
            const float arr[4] = {av.x, av.y, av.z, av.w};
            const float brr[8] = {b0.x,b0.y,b0.z,b0.w, b1.x,b1.y,b1.z,b1.w};
            #pragma unroll
            for (int i = 0; i < 4; ++i)
                #pragma unroll
                for (int j = 0; j < 8; ++j)
                    acc[i][j] = fmaf(arr[i], brr[j], acc[i][j]);
        }
    }

    #pragma unroll
    for (int i = 0; i < 4; ++i) {
        const int np = np0 + r0 + i;
        const float inv = 1.0f / colsum[b * NPS + np];
        const size_t ob = ((size_t)(ks * BB + b) * NPS + np) * DD + d0;
        *(float4*)&xsp[ob + c0]      = make_float4(acc[i][0]*inv, acc[i][1]*inv,
                                                   acc[i][2]*inv, acc[i][3]*inv);
        *(float4*)&xsp[ob + 64 + c0] = make_float4(acc[i][4]*inv, acc[i][5]*inv,
                                                   acc[i][6]*inv, acc[i][7]*inv);
    }
}

// K2b: xs = sum of the 4 split-K partials (deterministic, no atomics). grid 1024.
__global__ __launch_bounds__(256) void k2b_reduce_kernel(
    const float* __restrict__ xsp, float* __restrict__ xs)
{
    const size_t i = ((size_t)blockIdx.x * 256 + threadIdx.x) * 4;
    const float4 a = *(const float4*)&xsp[i];
    const float4 b = *(const float4*)&xsp[i + 1048576];
    const float4 c = *(const float4*)&xsp[i + 2097152];
    const float4 d = *(const float4*)&xsp[i + 3145728];
    *(float4*)&xs[i] = make_float4(a.x+b.x+c.x+d.x, a.y+b.y+c.y+d.y,
                                   a.z+b.z+c.z+d.z, a.w+b.w+c.w+d.w);
}

// ---------------------------------------------------------------------------
// K3: h = relu(xs @ w1 + b1)^2 per expert. 32 rows x 128 f, K=1024. grid 512.
// Streams w1 (268 MB): reg-prefetch dbuf, 1 barrier per K-tile. 4x4 acc.
// ---------------------------------------------------------------------------
__global__ __launch_bounds__(256) void k3_ffn1_kernel(
    const float* __restrict__ xs, const float* __restrict__ w1,
    const float* __restrict__ b1, float* __restrict__ h)
{
    __shared__ __align__(16) float aA[2][32][36];
    __shared__ __align__(16) float bB[2][32][128];
    const int tid = threadIdx.x;
    const int n  = blockIdx.x >> 4;
    const int f0 = (blockIdx.x & 15) * 128;
    const int r0 = (tid >> 5) * 4;
    const int c0 = (tid & 31) * 4;
    const int kk = tid & 31, rr0 = tid >> 5;

    size_t a_base[4];
    #pragma unroll
    for (int i = 0; i < 4; ++i) {
        const int rr = rr0 + 8 * i;
        a_base[i] = ((size_t)(rr >> 2) * NPS + n * PP + (rr & 3)) * DD + kk;
    }
    const size_t wrow = (size_t)n * DD;

    float  a_reg[4];
    float4 b_reg[4];
    #pragma unroll
    for (int i = 0; i < 4; ++i) a_reg[i] = xs[a_base[i]];
    #pragma unroll
    for (int i = 0; i < 4; ++i) {
        const int idx = tid + 256 * i;
        b_reg[i] = *(const float4*)&w1[(wrow + (idx >> 5)) * FF + f0 + (idx & 31) * 4];
    }

    float acc[4][4] = {};
    for (int kt = 0; kt < 32; ++kt) {
        const int buf = kt & 1;
        #pragma unroll
        for (int i = 0; i < 4; ++i) aA[buf][kk][rr0 + 8 * i] = a_reg[i];
        #pragma unroll
        for (int i = 0; i < 4; ++i) {
            const int idx = tid + 256 * i;
            *(float4*)&bB[buf][idx >> 5][(idx & 31) * 4] = b_reg[i];
        }
        __syncthreads();
        if (kt < 31) {
            const int k0 = (kt + 1) * 32;
            #pragma unroll
            for (int i = 0; i < 4; ++i) a_reg[i] = xs[a_base[i] + k0];
            #pragma unroll
            for (int i = 0; i < 4; ++i) {
                const int idx = tid + 256 * i;
                b_reg[i] = *(const float4*)&w1[(wrow + k0 + (idx >> 5)) * FF + f0 + (idx & 31) * 4];
            }
        }
        #pragma unroll
        for (int k = 0; k < 32; ++k) {
            const float4 av = *(const float4*)&aA[buf][k][r0];
            const float4 bv = *(const float4*)&bB[buf][k][c0];
            const float arr[4] = {av.x, av.y, av.z, av.w};
            const float brr[4] = {bv.x, bv.y, bv.z, bv.w};
            #pragma unroll
            for (int i = 0; i < 4; ++i)
                #pragma unroll
                for (int j = 0; j < 4; ++j)
                    acc[i][j] = fmaf(arr[i], brr[j], acc[i][j]);
        }
    }

    const float4 b1v = *(const float4*)&b1[n * FF + f0 + c0];
    const float bb1[4] = {b1v.x, b1v.y, b1v.z, b1v.w};
    #pragma unroll
    for (int i = 0; i < 4; ++i) {
        const int rr = r0 + i;
        float v[4];
        #pragma unroll
        for (int j = 0; j < 4; ++j) {
            const float t = fmaxf(acc[i][j] + bb1[j], 0.0f);
            v[j] = t * t;
        }
        *(float4*)&h[((size_t)(rr >> 2) * NPS + n * PP + (rr & 3)) * FF + f0 + c0] =
            make_float4(v[0], v[1], v[2], v[3]);
    }
}

// ---------------------------------------------------------------------------
// K4: y = h @ w2 + b2 per expert. 32 rows x 128 d, K=2048. grid 256.
// Streams w2 (268 MB): reg-prefetch dbuf, 1 barrier per K-tile. 4x4 acc.
// ---------------------------------------------------------------------------
__global__ __launch_bounds__(256) void k4_ffn2_kernel(
    const float* __restrict__ h, const float* __restrict__ w2,
    const float* __restrict__ b2, float* __restrict__ y)
{
    __shared__ __align__(16) float aA[2][32][36];
    __shared__ __align__(16) float bB[2][32][128];
    const int tid = threadIdx.x;
    const int n  = blockIdx.x >> 3;
    const int d0 = (blockIdx.x & 7) * 128;
    const int r0 = (tid >> 5) * 4;
    const int c0 = (tid & 31) * 4;
    const int kk = tid & 31, rr0 = tid >> 5;

    size_t a_base[4];
    #pragma unroll
    for (int i = 0; i < 4; ++i) {
        const int rr = rr0 + 8 * i;
        a_base[i] = ((size_t)(rr >> 2) * NPS + n * PP + (rr & 3)) * FF + kk;
    }
    const size_t wb = (size_t)n * FF;

    float  a_reg[4];
    float4 b_reg[4];
    #pragma unroll
    for (int i = 0; i < 4; ++i) a_reg[i] = h[a_base[i]];
    #pragma unroll
    for (int i = 0; i < 4; ++i) {
        const int idx = tid + 256 * i;
        b_reg[i] = *(const float4*)&w2[(wb + (idx >> 5)) * DD + d0 + (idx & 31) * 4];
    }

    float acc[4][4] = {};
    for (int kt = 0; kt < 64; ++kt) {
        const int buf = kt & 1;
        #pragma unroll
        for (int i = 0; i < 4; ++i) aA[buf][kk][rr0 + 8 * i] = a_reg[i];
        #pragma unroll
        for (int i = 0; i < 4; ++i) {
            const int idx = tid + 256 * i;
            *(float4*)&bB[buf][idx >> 5][(idx & 31) * 4] = b_reg[i];
        }
        __syncthreads();
        if (kt < 63) {
            const int k0 = (kt + 1) * 32;
            #pragma unroll
            for (int i = 0; i < 4; ++i) a_reg[i] = h[a_base[i] + k0];
            #pragma unroll
            for (int i = 0; i < 4; ++i) {
                const int idx = tid + 256 * i;
                b_reg[i] = *(const float4*)&w2[(wb + k0 + (idx >> 5)) * DD + d0 + (idx & 31) * 4];
            }
        }
        #pragma unroll
        for (int k = 0; k < 32; ++k) {
            const float4 av = *(const float4*)&aA[buf][k][r0];
            const float4 bv = *(const float4*)&bB[buf][k][c0];
            const float arr[4] = {av.x, av.y, av.z, av.w};
            const float brr[4] = {bv.x, bv.y, bv.z, bv.w};
            #pragma unroll
            for (int i = 0; i < 4; ++i)
                #pragma unroll
                for (int j = 0; j < 4; ++j)
                    acc[i][j] = fmaf(arr[i], brr[j], acc[i][j]);
        }
    }

    const float4 b2v = *(const float4*)&b2[n * DD + d0 + c0];
    #pragma unroll
    for (int i = 0; i < 4; ++i) {
        const int rr = r0 + i;
        const float4 v = make_float4(acc[i][0] + b2v.x, acc[i][1] + b2v.y,
                                     acc[i][2] + b2v.z, acc[i][3] + b2v.w);
        *(float4*)&y[((size_t)(rr >> 2) * NPS + n * PP + (rr & 3)) * DD + d0 + c0] = v;
    }
}

// ---------------------------------------------------------------------------
// K5: out[b,m,d] = sum_np combine[b,m,np] * y[b,np,d].  K=128.
// Tile 64 m x 128 d, 4x8 acc. grid = 8*32*8 = 2048. Single LDS buffer (small K),
// reg-prefetch, two barriers per K-tile.
// ---------------------------------------------------------------------------
__global__ __launch_bounds__(256) void k5_out_kernel(
    const float* __restrict__ Cbuf, const float* __restrict__ y,
    float* __restrict__ out)
{
    __shared__ __align__(16) float aA[32][68];
    __shared__ __align__(16) float bB[32][128];
    const int tid = threadIdx.x;
    const int bx  = blockIdx.x;
    const int dt = bx & 7;
    const int mt = (bx >> 3) & 31;
    const int b  = bx >> 8;
    const int d0 = dt * 128;
    const int m0 = mt * 64;
    const int r0 = (tid >> 4) * 4;
    const int c0 = (tid & 15) * 4;
    const int sa_r = tid >> 2;
    const int sa_k = (tid & 3) * 8;
    const float* ca = Cbuf + ((size_t)b * MM + m0 + sa_r) * NPS + sa_k;
    const size_t yb = (size_t)b * NPS;

    float4 ar0 = *(const float4*)(ca);
    float4 ar1 = *(const float4*)(ca + 4);
    float4 br[4];
    #pragma unroll
    for (int i = 0; i < 4; ++i) {
        const int idx = tid + 256 * i;
        br[i] = *(const float4*)&y[(yb + (idx >> 5)) * DD + d0 + (idx & 31) * 4];
    }

    float acc[4][8] = {};
    for (int kt = 0; kt < 4; ++kt) {
        {
            const float a8[8] = {ar0.x,ar0.y,ar0.z,ar0.w, ar1.x,ar1.y,ar1.z,ar1.w};
            #pragma unroll
            for (int j = 0; j < 8; ++j) aA[sa_k + j][sa_r] = a8[j];
            #pragma unroll
            for (int i = 0; i < 4; ++i) {
                const int idx = tid + 256 * i;
                *(float4*)&bB[idx >> 5][(idx & 31) * 4] = br[i];
            }
        }
        __syncthreads();
        if (kt < 3) {
            const int k0 = (kt + 1) * 32;
            ar0 = *(const float4*)(ca + k0);
            ar1 = *(const float4*)(ca + k0 + 4);
            #pragma unroll
            for (int i = 0; i < 4; ++i) {
                const int idx = tid + 256 * i;
                br[i] = *(const float4*)&y[(yb + k0 + (idx >> 5)) * DD + d0 + (idx & 31) * 4];
            }
        }
        #pragma unroll
        for (int k = 0; k < 32; ++k) {
            const float4 av = *(const float4*)&aA[k][r0];
            const float4 b0 = *(const float4*)&bB[k][c0];
            const float4 b1 = *(const float4*)&bB[k][64 + c0];
            const float arr[4] = {av.x, av.y, av.z, av.w};
            const float brr[8] = {b0.x,b0.y,b0.z,b0.w, b1.x,b1.y,b1.z,b1.w};
            #pragma unroll
            for (int i = 0; i < 4; ++i)
                #pragma unroll
                for (int j = 0; j < 8; ++j)
                    acc[i][j] = fmaf(arr[i], brr[j], acc[i][j]);
        }
        __syncthreads();   // single buffer: WAR guard before next stage-write
    }

    #pragma unroll
    for (int i = 0; i < 4; ++i) {
        const size_t ob = ((size_t)b * MM + m0 + r0 + i) * DD + d0;
        *(float4*)&out[ob + c0]      = make_float4(acc[i][0], acc[i][1], acc[i][2], acc[i][3]);
        *(float4*)&out[ob + 64 + c0] = make_float4(acc[i][4], acc[i][5], acc[i][6], acc[i][7]);
    }
}

// ---------------------------------------------------------------------------
extern "C" void kernel_launch(void* const* d_in, const int* in_sizes, int n_in,
                              void* d_out, int out_size, void* d_ws, size_t ws_size,
                              hipStream_t stream)
{
    const float* x   = (const float*)d_in[0];
    const float* phi = (const float*)d_in[1];
    const float* w1  = (const float*)d_in[2];
    const float* b1  = (const float*)d_in[3];
    const float* w2  = (const float*)d_in[4];
    const float* b2  = (const float*)d_in[5];
    float* out = (float*)d_out;
    float* ws  = (float*)d_ws;

    // workspace layout (floats): ~50.3 MB total
    float* Ebuf   = ws;                   // BMR*NPS      = 2,097,152
    float* Cbuf   = Ebuf  + 2097152;      // BMR*NPS      = 2,097,152
    float* xsp    = Cbuf  + 2097152;      // 4*BB*NPS*DD  = 4,194,304
    float* xsbuf  = xsp   + 4194304;      // BB*NPS*DD    = 1,048,576
    float* hbuf   = xsbuf + 1048576;      // BB*NPS*FF    = 2,097,152
    float* ybuf   = hbuf  + 2097152;      // BB*NPS*DD    = 1,048,576
    float* colsum = ybuf  + 1048576;      // BB*NPS       = 1,024

    hipMemsetAsync(colsum, 0, BB * NPS * sizeof(float), stream);
    hipLaunchKernelGGL(k1_logits_kernel, dim3(256), dim3(256), 0, stream,
                       x, phi, Ebuf, Cbuf, colsum);
    hipLaunchKernelGGL(k2_xs_kernel, dim3(512), dim3(256), 0, stream,
                       Ebuf, x, colsum, xsp);
    hipLaunchKernelGGL(k2b_reduce_kernel, dim3(1024), dim3(256), 0, stream,
                       xsp, xsbuf);
    hipLaunchKernelGGL(k3_ffn1_kernel, dim3(512), dim3(256), 0, stream,
                       xsbuf, w1, b1, hbuf);
    hipLaunchKernelGGL(k4_ffn2_kernel, dim3(256), dim3(256), 0, stream,
                       hbuf, w2, b2, ybuf);
    hipLaunchKernelGGL(k5_out_kernel, dim3(2048), dim3(256), 0, stream,
                       Cbuf, ybuf, out);
}